// Round 14
// baseline (4207.466 us; speedup 1.0000x reference)
//
#include <hip/hip_runtime.h>

namespace {
constexpr int T    = 2048;
constexpr int Bsz  = 4096;
constexpr int H    = 51;     // hidden units
constexpr int H4   = 204;    // 4*H gate rows
constexpr int NB   = 8;      // batches per block (cols 8-15 = finite phantom)
constexpr int BLK  = 1024;   // 16 waves; 2 blocks co-resident per CU
constexpr int GRID = Bsz / NB;  // 512 blocks = 2/CU
constexpr int NITER = T + 4;    // 2052 = 4*513
constexpr float SCI  = -1.44269504f;  // -log2(e): i,f,o gates
constexpr float SCGP =  2.88539008f;  // +2*log2(e): g gate
constexpr float SC2  = -2.88539008f;  // -2*log2(e): tanh(c) abs-form
}

typedef float    f32x4 __attribute__((ext_vector_type(4)));
typedef _Float16 f16x8 __attribute__((ext_vector_type(8)));
typedef unsigned short u16;

__device__ __forceinline__ float RCP(float x)  { return __builtin_amdgcn_rcpf(x); }
__device__ __forceinline__ float EXP2(float x) { return __builtin_amdgcn_exp2f(x); }

// Gi=-log2e*i, Gf=-log2e*f, Gg=+2log2e*g, Go=-log2e*o (pre-scaled into weights)
__device__ __forceinline__ float lstm_act(float Gi, float Gf, float Gg, float Go, float& c) {
  float ei = EXP2(Gi), ef = EXP2(Gf), eo = EXP2(Go), eg = EXP2(Gg);
  float pi = 1.f + ei, pf = 1.f + ef, pg = 1.f + eg, po = 1.f + eo;
  float pig = pi * pg;
  float num = fmaf(c, pig, (eg - 1.f) * pf);
  c = num * RCP(pig * pf);
  float ec = EXP2(SC2 * fabsf(c));
  float tc = copysignf(1.f - ec, c);
  return tc * RCP((1.f + ec) * po);
}

// LDS-visibility-only barrier (never drains vmcnt); per-workgroup HW barrier,
// so the two co-resident blocks sync independently and drift anti-phase.
#define BAR() asm volatile("s_waitcnt lgkmcnt(0)\n\ts_barrier" ::: "memory")
#define MF(A, B, C) __builtin_amdgcn_mfma_f32_16x16x32_f16((A), (B), (C), 0, 0, 0)

// Fragment k-map (validated r2-r13): lane = free(0..15)+16*q ; elem j: k = 32*sp+16*(j>>2)+4*q+(j&3)
// h-plane slot (b,k): sp=k>>5, kl=k&31, row=b+16*((kl>>2)&3), j=(kl&3)+4*(kl>>4)
// PL1: [buf4][sp2][row64][j8] shorts (h1 + x@51,52 + const1@53), 4-ring.
// PL2: [buf2][sp2][row64][j8] shorts (h2 + const1@53), parity ring.
// Rows for batches 8-15 are zero-input phantoms (finite, isolated in D cols 8-15).
// Schedule: interval s: L1 computes t=s with fragments PREFETCHED post-BAR(s-1);
//   L2 computes t2=s-2 (h1(s-2) prefetched a slot early; h2(s-3) read this slot);
//   head outputs t=s-3; xinj writes x(s+1) into PL1 buf s&3.

__global__ __launch_bounds__(BLK, 8) void lstm2_v14(
    const float* __restrict__ x,
    const float* __restrict__ Wih1, const float* __restrict__ Whh1,
    const float* __restrict__ bih1, const float* __restrict__ bhh1,
    const float* __restrict__ Wih2, const float* __restrict__ Whh2,
    const float* __restrict__ bih2, const float* __restrict__ bhh2,
    const float* __restrict__ Wlin, const float* __restrict__ blin,
    float* __restrict__ out) {
  extern __shared__ __align__(16) char smraw[];
  u16*   PL1 = (u16*)smraw;                              // [0, 8KB)
  u16*   PL2 = (u16*)(smraw + 8192);                     // [8KB, 12KB)
  auto   XB4 = (float4 (*)[32][4])(smraw + 12288);       // [12KB, 16KB) x chunks
  auto   OB  = (float (*)[8][40])(smraw + 16384);        // [16KB, 18.5KB)
  float* SW  = (float*)smraw;                            // init overlay [0, 41.6KB)

  const int tid  = threadIdx.x;
  const int lane = tid & 63;
  const int wid  = tid >> 6;
  const int a    = lane & 15;
  const int q    = lane >> 4;
  const int b0   = blockIdx.x * NB;
  const int rb   = lane * 8;

  // roles (v10 map): 7 L1 waves (13 tiles), 8 L2-ish waves (13 tiles), w14 head
  bool isL1 = false; int tA = -1, tB = -1;
  switch (wid) {
    case 0:  isL1 = true; tA = 0;  tB = 1;  break;
    case 1:  isL1 = true; tA = 4;  tB = 5;  break;
    case 2:  isL1 = true; tA = 8;  tB = 9;  break;
    case 3:  isL1 = true; tA = 10; tB = 11; break;
    case 4:  isL1 = true; tA = 2;  tB = 3;  break;
    case 5:  isL1 = true; tA = 6;  tB = 7;  break;
    case 6:  tA = 6;  tB = 7;  break;   // L2
    case 7:  isL1 = true; tA = 12; break;
    case 8:  tA = 0;  tB = 1;  break;   // L2
    case 9:  tA = 3;  tB = 4;  break;   // L2
    case 10: tA = 8;  tB = 9;  break;   // L2
    case 11: tA = 10; tB = 11; break;   // L2
    case 12: tA = 2;  break;            // L2
    case 13: tA = 5;  break;            // L2
    case 14: break;                     // head
    case 15: tA = 12; break;            // L2 + xinj chores
  }
  const bool isHead = (wid == 14);
  const bool isXinj = (wid == 15);
  const bool isL2   = (!isL1) && (tA >= 0);

  // ---------------- init: weight A-fragments (pre-scaled single fp16) ----------------
  f16x8 wA[2][4];   // [tile][sp]; L1 uses sp0-1; L2: sp0-1 Wih2+bias2, sp2-3 Whh2
  f16x8 hA[2];      // head: Wlin + blin

  for (int i = tid; i < H4 * H; i += BLK) SW[i] = Whh1[i];
  __syncthreads();
  if (isL1) {
#pragma unroll
    for (int ti = 0; ti < 2; ++ti) {
      const int t = ti ? tB : tA;
      if (t >= 0) {
        const int  rp   = 16 * t + a;
        const bool vld  = (rp < H4);
        const int  gate = rp & 3;
        const int  wrow = gate * H + (rp >> 2);
        const float sc  = (gate == 2) ? SCGP : SCI;
#pragma unroll
        for (int sp = 0; sp < 2; ++sp)
#pragma unroll
          for (int j = 0; j < 8; ++j) {
            const int k = 32 * sp + 16 * (j >> 2) + 4 * q + (j & 3);
            float val = 0.f;
            if (vld) {
              if (k < H)           val = SW[wrow * H + k];
              else if (k == H)     val = Wih1[wrow * 2 + 0];
              else if (k == H + 1) val = Wih1[wrow * 2 + 1];
              else if (k == H + 2) val = bih1[wrow] + bhh1[wrow];
            }
            wA[ti][sp][j] = (_Float16)(val * sc);
          }
      }
    }
  }
  __syncthreads();
  for (int i = tid; i < H4 * H; i += BLK) SW[i] = Wih2[i];
  __syncthreads();
  if (isL2) {
#pragma unroll
    for (int ti = 0; ti < 2; ++ti) {
      const int t = ti ? tB : tA;
      if (t >= 0) {
        const int  rp   = 16 * t + a;
        const bool vld  = (rp < H4);
        const int  gate = rp & 3;
        const int  wrow = gate * H + (rp >> 2);
        const float sc  = (gate == 2) ? SCGP : SCI;
#pragma unroll
        for (int sp = 0; sp < 2; ++sp)
#pragma unroll
          for (int j = 0; j < 8; ++j) {
            const int k = 32 * sp + 16 * (j >> 2) + 4 * q + (j & 3);
            float val = 0.f;
            if (vld) {
              if (k < H)           val = SW[wrow * H + k];
              else if (k == H + 2) val = bih2[wrow] + bhh2[wrow];
            }
            wA[ti][sp][j] = (_Float16)(val * sc);
          }
      }
    }
  }
  __syncthreads();
  for (int i = tid; i < H4 * H; i += BLK) SW[i] = Whh2[i];
  __syncthreads();
  if (isL2) {
#pragma unroll
    for (int ti = 0; ti < 2; ++ti) {
      const int t = ti ? tB : tA;
      if (t >= 0) {
        const int  rp   = 16 * t + a;
        const bool vld  = (rp < H4);
        const int  gate = rp & 3;
        const int  wrow = gate * H + (rp >> 2);
        const float sc  = (gate == 2) ? SCGP : SCI;
#pragma unroll
        for (int sp = 2; sp < 4; ++sp)
#pragma unroll
          for (int j = 0; j < 8; ++j) {
            const int kp = 32 * (sp - 2) + 16 * (j >> 2) + 4 * q + (j & 3);
            float val = (vld && kp < H) ? SW[wrow * H + kp] * sc : 0.f;
            wA[ti][sp][j] = (_Float16)val;
          }
      }
    }
  }
  if (isHead) {
#pragma unroll
    for (int sp = 0; sp < 2; ++sp)
#pragma unroll
      for (int j = 0; j < 8; ++j) {
        const int kp = 32 * sp + 16 * (j >> 2) + 4 * q + (j & 3);
        float val = 0.f;
        if (a == 0) {
          if (kp < H)           val = Wlin[kp];
          else if (kp == H + 2) val = blin[0];
        }
        hA[sp][j] = (_Float16)val;
      }
  }
  __syncthreads();   // SW dead from here

  // ---------------- runtime LDS init ----------------
  for (int i = tid; i < 6144; i += BLK) PL1[i] = 0;   // PL1 (4096) + PL2 (2048)
  if (isXinj) {  // preload x chunk 0 (steps 0..31): 8 batches x 2 = 4 float4/step
#pragma unroll
    for (int k = 0; k < 2; ++k) {
      const int idx = lane + 64 * k, st = idx >> 2, v = idx & 3;
      XB4[0][st][v] = *(const float4*)(x + (size_t)st * Bsz * 2 + b0 * 2 + v * 4);
    }
  }
  __syncthreads();
  if (tid < 16) {  // const-1 (fp16 1.0) at k=53 slot of every buffer
#pragma unroll
    for (int buf = 0; buf < 4; ++buf) PL1[buf * 1024 + 512 + (tid + 16) * 8 + 5] = 0x3C00;
#pragma unroll
    for (int buf = 0; buf < 2; ++buf) PL2[buf * 1024 + 512 + (tid + 16) * 8 + 5] = 0x3C00;
  }
  __syncthreads();
  // x slots: k=51 -> (sp1,row=bb,j=7) ; k=52 -> (sp1,row=bb+16,j=4); bb<8 real
  const int bb_x = lane & 7, f_x = (lane >> 3) & 1;
  const int xslot = (f_x == 0) ? bb_x * 8 + 7 : (bb_x + 16) * 8 + 4;
  if (isXinj && lane < 16) {  // inject x(0) into PL1 buf 3 (read at interval 0)
    const float xv = ((const float*)&XB4[0][0][0])[bb_x * 2 + f_x];
    *(_Float16*)&PL1[3 * 1024 + 512 + xslot] = (_Float16)xv;
  }
  __syncthreads();

  // act write slots (lane owns u = 4*tile+q, batch = a; a>=8 phantom, finite)
  int  widx0 = 0, widx1 = 0;
  bool uval0 = false, uval1 = false;
  if (tA >= 0) {
    const int u = 4 * tA + q;
    if (u < H) {
      uval0 = true;
      const int spl = u >> 5, kl = u & 31;
      widx0 = spl * 512 + (a + 16 * ((kl >> 2) & 3)) * 8 + ((kl & 3) + 4 * (kl >> 4));
    }
  }
  if (tB >= 0) {
    const int u = 4 * tB + q;
    if (u < H) {
      uval1 = true;
      const int spl = u >> 5, kl = u & 31;
      widx1 = spl * 512 + (a + 16 * ((kl >> 2) & 3)) * 8 + ((kl & 3) + 4 * (kl >> 4));
    }
  }

  float cc0 = 0.f, cc1 = 0.f;
  const f32x4 z4 = {0.f, 0.f, 0.f, 0.f};

  if (isL1) {
    // ================= L1 role loop =================
    f16x8 pf0 = *(const f16x8*)&PL1[3 * 1024 + rb];
    f16x8 pf1 = *(const f16x8*)&PL1[3 * 1024 + 512 + rb];

#define L1B(S, B)                                                               \
  { const int s = (S);                                                          \
    f32x4 dA = MF(wA[0][0], pf0, z4); dA = MF(wA[0][1], pf1, dA);               \
    f32x4 dB = z4;                                                              \
    if (tB >= 0) { dB = MF(wA[1][0], pf0, z4); dB = MF(wA[1][1], pf1, dB); }    \
    if (s < T) {                                                                \
      const float h0 = lstm_act(dA[0], dA[1], dA[2], dA[3], cc0);               \
      if (uval0) *(_Float16*)&PL1[(B) * 1024 + widx0] = (_Float16)h0;           \
      if (tB >= 0) {                                                            \
        const float h1 = lstm_act(dB[0], dB[1], dB[2], dB[3], cc1);             \
        if (uval1) *(_Float16*)&PL1[(B) * 1024 + widx1] = (_Float16)h1;         \
      }                                                                         \
    }                                                                           \
    BAR();                                                                      \
    pf0 = *(const f16x8*)&PL1[(B) * 1024 + rb];                                 \
    pf1 = *(const f16x8*)&PL1[(B) * 1024 + 512 + rb];                           \
  }

    for (int s0 = 0; s0 < NITER; s0 += 4) {
      L1B(s0 + 0, 0) L1B(s0 + 1, 1) L1B(s0 + 2, 2) L1B(s0 + 3, 3)
    }
#undef L1B
  } else {
    // ================= L2 / head / xinj role loop =================
    f16x8 pc0 = *(const f16x8*)&PL1[2 * 1024 + rb];   // zeros at start
    f16x8 pc1 = *(const f16x8*)&PL1[2 * 1024 + 512 + rb];
    float4 xcr0 = {0,0,0,0}, xcr1 = {0,0,0,0};

#define BB(S, B)                                                                \
  { const int s = (S); constexpr int P = (B) & 1;                               \
    f16x8 bq0 = *(const f16x8*)&PL2[(P ^ 1) * 1024 + rb];                       \
    f16x8 bq1 = *(const f16x8*)&PL2[(P ^ 1) * 1024 + 512 + rb];                 \
    if (isXinj) {                                                               \
      const int ph = s & 31;                                                    \
      if (ph == 0) {                                                            \
        if (s + 32 < T) {                                                       \
          const int i0 = lane, i1 = lane + 64;                                  \
          xcr0 = *(const float4*)(x + (size_t)(s + 32 + (i0 >> 2)) * Bsz * 2 + b0 * 2 + (i0 & 3) * 4); \
          xcr1 = *(const float4*)(x + (size_t)(s + 32 + (i1 >> 2)) * Bsz * 2 + b0 * 2 + (i1 & 3) * 4); \
        }                                                                       \
      } else if (ph == 1) {                                                     \
        if (s + 31 < T) {                                                       \
          const int buf = ((s >> 5) + 1) & 1;                                   \
          const int i0 = lane, i1 = lane + 64;                                  \
          XB4[buf][i0 >> 2][i0 & 3] = xcr0;                                     \
          XB4[buf][i1 >> 2][i1 & 3] = xcr1;                                     \
        }                                                                       \
      } else if (ph == 3 && s >= 35) {                                          \
        const int f = (s - 35) >> 5;                                            \
        const int r = lane >> 3, c0 = (lane & 7) * 4;                           \
        const float4 v0 = *(const float4*)&OB[f & 1][r][c0];                    \
        *(float4*)(out + (size_t)(b0 + r) * T + f * 32 + c0) = v0;              \
      }                                                                         \
    }                                                                           \
    f32x4 dA = z4, dB = z4;                                                     \
    if (tA >= 0) {                                                              \
      dA = MF(wA[0][0], pc0, z4); dA = MF(wA[0][1], pc1, dA);                   \
      if (tB >= 0) { dB = MF(wA[1][0], pc0, z4); dB = MF(wA[1][1], pc1, dB); }  \
      pc0 = *(const f16x8*)&PL1[(((B) + 3) & 3) * 1024 + rb];                   \
      pc1 = *(const f16x8*)&PL1[(((B) + 3) & 3) * 1024 + 512 + rb];             \
      dA = MF(wA[0][2], bq0, dA); dA = MF(wA[0][3], bq1, dA);                   \
      if (tB >= 0) { dB = MF(wA[1][2], bq0, dB); dB = MF(wA[1][3], bq1, dB); }  \
      if (s >= 2 && s <= T + 1) {                                               \
        const float h0 = lstm_act(dA[0], dA[1], dA[2], dA[3], cc0);             \
        if (uval0) *(_Float16*)&PL2[P * 1024 + widx0] = (_Float16)h0;           \
        if (tB >= 0) {                                                          \
          const float h1 = lstm_act(dB[0], dB[1], dB[2], dB[3], cc1);           \
          if (uval1) *(_Float16*)&PL2[P * 1024 + widx1] = (_Float16)h1;         \
        }                                                                       \
      }                                                                         \
    }                                                                           \
    if (isHead) {                                                               \
      f32x4 dh = MF(hA[0], bq0, z4); dh = MF(hA[1], bq1, dh);                   \
      if (s >= 3 && s <= T + 2 && lane < 8)                                     \
        OB[((s - 3) >> 5) & 1][lane][(s - 3) & 31] = dh[0];                     \
    }                                                                           \
    if (isXinj && lane < 16 && s + 1 < T) {                                     \
      const int st = (s + 1) & 31, cb = ((s + 1) >> 5) & 1;                     \
      const float xv = ((const float*)&XB4[cb][st][0])[bb_x * 2 + f_x];         \
      *(_Float16*)&PL1[(B) * 1024 + 512 + xslot] = (_Float16)xv;                \
    }                                                                           \
    BAR();                                                                      \
  }

    for (int s0 = 0; s0 < NITER; s0 += 4) {
      BB(s0 + 0, 0) BB(s0 + 1, 1) BB(s0 + 2, 2) BB(s0 + 3, 3)
    }
#undef BB
  }
}

extern "C" void kernel_launch(void* const* d_in, const int* in_sizes, int n_in,
                              void* d_out, int out_size, void* d_ws, size_t ws_size,
                              hipStream_t stream) {
  (void)in_sizes; (void)n_in; (void)d_ws; (void)ws_size; (void)out_size;
  const float* x    = (const float*)d_in[0];
  const float* Wih1 = (const float*)d_in[1];
  const float* Whh1 = (const float*)d_in[2];
  const float* bih1 = (const float*)d_in[3];
  const float* bhh1 = (const float*)d_in[4];
  const float* Wih2 = (const float*)d_in[5];
  const float* Whh2 = (const float*)d_in[6];
  const float* bih2 = (const float*)d_in[7];
  const float* bhh2 = (const float*)d_in[8];
  const float* Wlin = (const float*)d_in[9];
  const float* blin = (const float*)d_in[10];
  float* out = (float*)d_out;

  const size_t shmem = (size_t)H4 * H * sizeof(float);  // 41616 B (init overlay)
  hipFuncSetAttribute((const void*)lstm2_v14,
                      hipFuncAttributeMaxDynamicSharedMemorySize, (int)shmem);

  hipLaunchKernelGGL(lstm2_v14, dim3(GRID), dim3(BLK), shmem, stream,
                     x, Wih1, Whh1, bih1, bhh1, Wih2, Whh2, bih2, bhh2,
                     Wlin, blin, out);
}

// Round 15
// 1189.133 us; speedup vs baseline: 3.5383x; 3.5383x over previous
//
#include <hip/hip_runtime.h>

namespace {
constexpr int T    = 2048;
constexpr int Bsz  = 4096;
constexpr int H    = 51;     // hidden units
constexpr int H4   = 204;    // 4*H gate rows
constexpr int NB   = 16;     // batches per block = MFMA free dim
constexpr int BLK  = 1024;   // 16 waves, 4 per SIMD
constexpr int GRID = Bsz / NB;  // 256 blocks = 1/CU
constexpr int NITER = T + 4;    // 2052 = 4*513
constexpr float SCI  = -1.44269504f;  // -log2(e): i,f,o gates
constexpr float SCGP =  2.88539008f;  // +2*log2(e): g gate
constexpr float SC2  = -2.88539008f;  // -2*log2(e): tanh(c) abs-form
}

typedef float    f32x4 __attribute__((ext_vector_type(4)));
typedef _Float16 f16x8 __attribute__((ext_vector_type(8)));
typedef unsigned short u16;

__device__ __forceinline__ float RCP(float x)  { return __builtin_amdgcn_rcpf(x); }
__device__ __forceinline__ float EXP2(float x) { return __builtin_amdgcn_exp2f(x); }

// Gi=-log2e*i, Gf=-log2e*f, Gg=+2log2e*g, Go=-log2e*o (pre-scaled into weights)
__device__ __forceinline__ float lstm_act(float Gi, float Gf, float Gg, float Go, float& c) {
  float ei = EXP2(Gi), ef = EXP2(Gf), eo = EXP2(Go), eg = EXP2(Gg);
  float pi = 1.f + ei, pf = 1.f + ef, pg = 1.f + eg, po = 1.f + eo;
  float pig = pi * pg;
  float num = fmaf(c, pig, (eg - 1.f) * pf);
  c = num * RCP(pig * pf);
  float ec = EXP2(SC2 * fabsf(c));
  float tc = copysignf(1.f - ec, c);
  return tc * RCP((1.f + ec) * po);
}

// LDS-visibility-only barrier (never drains vmcnt)
#define BAR() asm volatile("s_waitcnt lgkmcnt(0)\n\ts_barrier" ::: "memory")
#define MF(A, B, C) __builtin_amdgcn_mfma_f32_16x16x32_f16((A), (B), (C), 0, 0, 0)

// Fragment k-map (validated r2-r14): lane = free(0..15)+16*q ; elem j: k = 32*sp+16*(j>>2)+4*q+(j&3)
// h-plane slot (b,k): sp=k>>5, kl=k&31, row=b+16*((kl>>2)&3), j=(kl&3)+4*(kl>>4)
// PL1: [buf4][sp2][row64][j8] shorts (h1 + x@51,52 + const1@53), 4-ring.
// PL2: [buf2][sp2][row64][j8] shorts (h2 + const1@53), 2-ring.
// Schedule: interval s: L1 computes t=s with fragments PREFETCHED post-BAR(s-1);
//   L2 computes t2=s-2 (h1(s-2) prefetched a slot early; h2(s-3) read this slot);
//   head outputs t=s-3; xinj writes x(s+1) into PL1 buf s&3.

__global__ __launch_bounds__(BLK, 4) void lstm2_v10(
    const float* __restrict__ x,
    const float* __restrict__ Wih1, const float* __restrict__ Whh1,
    const float* __restrict__ bih1, const float* __restrict__ bhh1,
    const float* __restrict__ Wih2, const float* __restrict__ Whh2,
    const float* __restrict__ bih2, const float* __restrict__ bhh2,
    const float* __restrict__ Wlin, const float* __restrict__ blin,
    float* __restrict__ out) {
  extern __shared__ __align__(16) char smraw[];
  u16*   PL1 = (u16*)smraw;                              // [0, 8KB)
  u16*   PL2 = (u16*)(smraw + 8192);                     // [8KB, 12KB)
  auto   XB  = (float2 (*)[32][16])(smraw + 12288);      // [12KB, 20KB)
  auto   OB  = (float (*)[16][40])(smraw + 20480);       // [20KB, 25.6KB)
  float* SW  = (float*)smraw;                            // init overlay [0, 41.6KB)

  const int tid  = threadIdx.x;
  const int lane = tid & 63;
  const int wid  = tid >> 6;
  const int a    = lane & 15;
  const int q    = lane >> 4;
  const int b0   = blockIdx.x * NB;
  const int rb   = lane * 8;

  // roles: 7 L1 waves (13 tiles), 8 L2-ish waves (13 tiles; w15 also xinj chores),
  // w14 = head. SIMD act balance 7/7/6+head/6+chores.
  bool isL1 = false; int tA = -1, tB = -1;
  switch (wid) {
    case 0:  isL1 = true; tA = 0;  tB = 1;  break;
    case 1:  isL1 = true; tA = 4;  tB = 5;  break;
    case 2:  isL1 = true; tA = 8;  tB = 9;  break;
    case 3:  isL1 = true; tA = 10; tB = 11; break;
    case 4:  isL1 = true; tA = 2;  tB = 3;  break;
    case 5:  isL1 = true; tA = 6;  tB = 7;  break;
    case 6:  tA = 6;  tB = 7;  break;   // L2
    case 7:  isL1 = true; tA = 12; break;
    case 8:  tA = 0;  tB = 1;  break;   // L2
    case 9:  tA = 3;  tB = 4;  break;   // L2
    case 10: tA = 8;  tB = 9;  break;   // L2
    case 11: tA = 10; tB = 11; break;   // L2
    case 12: tA = 2;  break;            // L2
    case 13: tA = 5;  break;            // L2
    case 14: break;                     // head
    case 15: tA = 12; break;            // L2 + xinj chores
  }
  const bool isHead = (wid == 14);
  const bool isXinj = (wid == 15);
  const bool isL2   = (!isL1) && (tA >= 0);

  // ---------------- init: weight A-fragments (pre-scaled single fp16) ----------------
  f16x8 wA[2][4];   // [tile][sp]; L1 uses sp0-1; L2: sp0-1 Wih2+bias2, sp2-3 Whh2
  f16x8 hA[2];      // head: Wlin + blin

  for (int i = tid; i < H4 * H; i += BLK) SW[i] = Whh1[i];
  __syncthreads();
  if (isL1) {
#pragma unroll
    for (int ti = 0; ti < 2; ++ti) {
      const int t = ti ? tB : tA;
      if (t >= 0) {
        const int  rp   = 16 * t + a;
        const bool vld  = (rp < H4);
        const int  gate = rp & 3;
        const int  wrow = gate * H + (rp >> 2);
        const float sc  = (gate == 2) ? SCGP : SCI;
#pragma unroll
        for (int sp = 0; sp < 2; ++sp)
#pragma unroll
          for (int j = 0; j < 8; ++j) {
            const int k = 32 * sp + 16 * (j >> 2) + 4 * q + (j & 3);
            float val = 0.f;
            if (vld) {
              if (k < H)           val = SW[wrow * H + k];
              else if (k == H)     val = Wih1[wrow * 2 + 0];
              else if (k == H + 1) val = Wih1[wrow * 2 + 1];
              else if (k == H + 2) val = bih1[wrow] + bhh1[wrow];
            }
            wA[ti][sp][j] = (_Float16)(val * sc);
          }
      }
    }
  }
  __syncthreads();
  for (int i = tid; i < H4 * H; i += BLK) SW[i] = Wih2[i];
  __syncthreads();
  if (isL2) {
#pragma unroll
    for (int ti = 0; ti < 2; ++ti) {
      const int t = ti ? tB : tA;
      if (t >= 0) {
        const int  rp   = 16 * t + a;
        const bool vld  = (rp < H4);
        const int  gate = rp & 3;
        const int  wrow = gate * H + (rp >> 2);
        const float sc  = (gate == 2) ? SCGP : SCI;
#pragma unroll
        for (int sp = 0; sp < 2; ++sp)
#pragma unroll
          for (int j = 0; j < 8; ++j) {
            const int k = 32 * sp + 16 * (j >> 2) + 4 * q + (j & 3);
            float val = 0.f;
            if (vld) {
              if (k < H)           val = SW[wrow * H + k];
              else if (k == H + 2) val = bih2[wrow] + bhh2[wrow];
            }
            wA[ti][sp][j] = (_Float16)(val * sc);
          }
      }
    }
  }
  __syncthreads();
  for (int i = tid; i < H4 * H; i += BLK) SW[i] = Whh2[i];
  __syncthreads();
  if (isL2) {
#pragma unroll
    for (int ti = 0; ti < 2; ++ti) {
      const int t = ti ? tB : tA;
      if (t >= 0) {
        const int  rp   = 16 * t + a;
        const bool vld  = (rp < H4);
        const int  gate = rp & 3;
        const int  wrow = gate * H + (rp >> 2);
        const float sc  = (gate == 2) ? SCGP : SCI;
#pragma unroll
        for (int sp = 2; sp < 4; ++sp)
#pragma unroll
          for (int j = 0; j < 8; ++j) {
            const int kp = 32 * (sp - 2) + 16 * (j >> 2) + 4 * q + (j & 3);
            float val = (vld && kp < H) ? SW[wrow * H + kp] * sc : 0.f;
            wA[ti][sp][j] = (_Float16)val;
          }
      }
    }
  }
  if (isHead) {
#pragma unroll
    for (int sp = 0; sp < 2; ++sp)
#pragma unroll
      for (int j = 0; j < 8; ++j) {
        const int kp = 32 * sp + 16 * (j >> 2) + 4 * q + (j & 3);
        float val = 0.f;
        if (a == 0) {
          if (kp < H)           val = Wlin[kp];
          else if (kp == H + 2) val = blin[0];
        }
        hA[sp][j] = (_Float16)val;
      }
  }
  __syncthreads();   // SW dead from here

  // ---------------- runtime LDS init ----------------
  for (int i = tid; i < 6144; i += BLK) PL1[i] = 0;   // PL1 (4096) + PL2 (2048)
  if (isXinj) {  // preload x chunk 0 (steps 0..31): 64 lanes x 4 float4
#pragma unroll
    for (int k = 0; k < 4; ++k) {
      const int idx = lane + 64 * k, st = idx >> 3, bc = (idx & 7) * 2;
      *(float4*)&XB[0][st][bc] = *(const float4*)(x + ((size_t)st * Bsz + b0 + bc) * 2);
    }
  }
  __syncthreads();
  if (tid < 16) {  // const-1 (fp16 1.0) at k=53 slot of every buffer
#pragma unroll
    for (int buf = 0; buf < 4; ++buf) PL1[buf * 1024 + 512 + (tid + 16) * 8 + 5] = 0x3C00;
#pragma unroll
    for (int buf = 0; buf < 2; ++buf) PL2[buf * 1024 + 512 + (tid + 16) * 8 + 5] = 0x3C00;
  }
  __syncthreads();
  const int xslot = ((lane >> 4) == 0) ? (lane & 15) * 8 + 7 : ((lane & 15) + 16) * 8 + 4;
  if (isXinj && lane < 32) {  // inject x(0) into PL1 buf 3 (read at interval 0)
    const float xv = ((const float*)&XB[0][0][0])[(lane & 15) * 2 + (lane >> 4)];
    *(_Float16*)&PL1[3 * 1024 + 512 + xslot] = (_Float16)xv;
  }
  __syncthreads();

  // act write slots (lane owns u = 4*tile+q, batch = a)
  int  widx0 = 0, widx1 = 0;
  bool uval0 = false, uval1 = false;
  if (tA >= 0) {
    const int u = 4 * tA + q;
    if (u < H) {
      uval0 = true;
      const int spl = u >> 5, kl = u & 31;
      widx0 = spl * 512 + (a + 16 * ((kl >> 2) & 3)) * 8 + ((kl & 3) + 4 * (kl >> 4));
    }
  }
  if (tB >= 0) {
    const int u = 4 * tB + q;
    if (u < H) {
      uval1 = true;
      const int spl = u >> 5, kl = u & 31;
      widx1 = spl * 512 + (a + 16 * ((kl >> 2) & 3)) * 8 + ((kl & 3) + 4 * (kl >> 4));
    }
  }

  float cc0 = 0.f, cc1 = 0.f;
  const f32x4 z4 = {0.f, 0.f, 0.f, 0.f};

  if (isL1) {
    // ================= L1 role loop =================
    f16x8 pf0 = *(const f16x8*)&PL1[3 * 1024 + rb];
    f16x8 pf1 = *(const f16x8*)&PL1[3 * 1024 + 512 + rb];

#define L1B(S, B)                                                               \
  { const int s = (S);                                                          \
    f32x4 dA = MF(wA[0][0], pf0, z4); dA = MF(wA[0][1], pf1, dA);               \
    f32x4 dB = z4;                                                              \
    if (tB >= 0) { dB = MF(wA[1][0], pf0, z4); dB = MF(wA[1][1], pf1, dB); }    \
    if (s < T) {                                                                \
      const float h0 = lstm_act(dA[0], dA[1], dA[2], dA[3], cc0);               \
      if (uval0) *(_Float16*)&PL1[(B) * 1024 + widx0] = (_Float16)h0;           \
      if (tB >= 0) {                                                            \
        const float h1 = lstm_act(dB[0], dB[1], dB[2], dB[3], cc1);             \
        if (uval1) *(_Float16*)&PL1[(B) * 1024 + widx1] = (_Float16)h1;         \
      }                                                                         \
    }                                                                           \
    BAR();                                                                      \
    pf0 = *(const f16x8*)&PL1[(B) * 1024 + rb];                                 \
    pf1 = *(const f16x8*)&PL1[(B) * 1024 + 512 + rb];                           \
  }

    for (int s0 = 0; s0 < NITER; s0 += 4) {
      L1B(s0 + 0, 0) L1B(s0 + 1, 1) L1B(s0 + 2, 2) L1B(s0 + 3, 3)
    }
#undef L1B
  } else {
    // ================= L2 / head / xinj role loop =================
    f16x8 pc0 = *(const f16x8*)&PL1[2 * 1024 + rb];   // garbage-safe (zeros)
    f16x8 pc1 = *(const f16x8*)&PL1[2 * 1024 + 512 + rb];
    float4 xcr0 = {0,0,0,0}, xcr1 = {0,0,0,0}, xcr2 = {0,0,0,0}, xcr3 = {0,0,0,0};

#define BB(S, B)                                                                \
  { const int s = (S); constexpr int P = (B) & 1;                               \
    f16x8 bq0 = *(const f16x8*)&PL2[(P ^ 1) * 1024 + rb];                       \
    f16x8 bq1 = *(const f16x8*)&PL2[(P ^ 1) * 1024 + 512 + rb];                 \
    if (isXinj) {                                                               \
      const int ph = s & 31;                                                    \
      if (ph == 0) {                                                            \
        if (s + 32 < T) {                                                       \
          const int i0 = lane, i1 = lane + 64, i2 = lane + 128, i3 = lane + 192;\
          xcr0 = *(const float4*)(x + ((size_t)(s + 32 + (i0 >> 3)) * Bsz + b0 + (i0 & 7) * 2) * 2); \
          xcr1 = *(const float4*)(x + ((size_t)(s + 32 + (i1 >> 3)) * Bsz + b0 + (i1 & 7) * 2) * 2); \
          xcr2 = *(const float4*)(x + ((size_t)(s + 32 + (i2 >> 3)) * Bsz + b0 + (i2 & 7) * 2) * 2); \
          xcr3 = *(const float4*)(x + ((size_t)(s + 32 + (i3 >> 3)) * Bsz + b0 + (i3 & 7) * 2) * 2); \
        }                                                                       \
      } else if (ph == 1) {                                                     \
        if (s + 31 < T) {                                                       \
          const int buf = ((s >> 5) + 1) & 1;                                   \
          const int i0 = lane, i1 = lane + 64, i2 = lane + 128, i3 = lane + 192;\
          *(float4*)&XB[buf][i0 >> 3][(i0 & 7) * 2] = xcr0;                     \
          *(float4*)&XB[buf][i1 >> 3][(i1 & 7) * 2] = xcr1;                     \
          *(float4*)&XB[buf][i2 >> 3][(i2 & 7) * 2] = xcr2;                     \
          *(float4*)&XB[buf][i3 >> 3][(i3 & 7) * 2] = xcr3;                     \
        }                                                                       \
      } else if (ph == 3 && s >= 35) {                                          \
        const int f = (s - 35) >> 5;                                            \
        const int r = lane >> 2, c0 = (lane & 3) * 8;                           \
        const float4 v0 = *(const float4*)&OB[f & 1][r][c0];                    \
        const float4 v1 = *(const float4*)&OB[f & 1][r][c0 + 4];                \
        *(float4*)(out + (size_t)(b0 + r) * T + f * 32 + c0)     = v0;          \
        *(float4*)(out + (size_t)(b0 + r) * T + f * 32 + c0 + 4) = v1;          \
      }                                                                         \
    }                                                                           \
    f32x4 dA = z4, dB = z4;                                                     \
    if (tA >= 0) {                                                              \
      dA = MF(wA[0][0], pc0, z4); dA = MF(wA[0][1], pc1, dA);                   \
      if (tB >= 0) { dB = MF(wA[1][0], pc0, z4); dB = MF(wA[1][1], pc1, dB); }  \
      pc0 = *(const f16x8*)&PL1[(((B) + 3) & 3) * 1024 + rb];                   \
      pc1 = *(const f16x8*)&PL1[(((B) + 3) & 3) * 1024 + 512 + rb];             \
      dA = MF(wA[0][2], bq0, dA); dA = MF(wA[0][3], bq1, dA);                   \
      if (tB >= 0) { dB = MF(wA[1][2], bq0, dB); dB = MF(wA[1][3], bq1, dB); }  \
      if (s >= 2 && s <= T + 1) {                                               \
        const float h0 = lstm_act(dA[0], dA[1], dA[2], dA[3], cc0);             \
        if (uval0) *(_Float16*)&PL2[P * 1024 + widx0] = (_Float16)h0;           \
        if (tB >= 0) {                                                          \
          const float h1 = lstm_act(dB[0], dB[1], dB[2], dB[3], cc1);           \
          if (uval1) *(_Float16*)&PL2[P * 1024 + widx1] = (_Float16)h1;         \
        }                                                                       \
      }                                                                         \
    }                                                                           \
    if (isHead) {                                                               \
      f32x4 dh = MF(hA[0], bq0, z4); dh = MF(hA[1], bq1, dh);                   \
      if (s >= 3 && s <= T + 2 && lane < 16)                                    \
        OB[((s - 3) >> 5) & 1][lane][(s - 3) & 31] = dh[0];                     \
    }                                                                           \
    if (isXinj && lane < 32 && s + 1 < T) {                                     \
      const int st = (s + 1) & 31, cb = ((s + 1) >> 5) & 1;                     \
      const float xv = ((const float*)&XB[cb][st][0])[(lane & 15) * 2 + (lane >> 4)]; \
      *(_Float16*)&PL1[(B) * 1024 + 512 + xslot] = (_Float16)xv;                \
    }                                                                           \
    BAR();                                                                      \
  }

    for (int s0 = 0; s0 < NITER; s0 += 4) {
      BB(s0 + 0, 0) BB(s0 + 1, 1) BB(s0 + 2, 2) BB(s0 + 3, 3)
    }
#undef BB
  }
}

extern "C" void kernel_launch(void* const* d_in, const int* in_sizes, int n_in,
                              void* d_out, int out_size, void* d_ws, size_t ws_size,
                              hipStream_t stream) {
  (void)in_sizes; (void)n_in; (void)d_ws; (void)ws_size; (void)out_size;
  const float* x    = (const float*)d_in[0];
  const float* Wih1 = (const float*)d_in[1];
  const float* Whh1 = (const float*)d_in[2];
  const float* bih1 = (const float*)d_in[3];
  const float* bhh1 = (const float*)d_in[4];
  const float* Wih2 = (const float*)d_in[5];
  const float* Whh2 = (const float*)d_in[6];
  const float* bih2 = (const float*)d_in[7];
  const float* bhh2 = (const float*)d_in[8];
  const float* Wlin = (const float*)d_in[9];
  const float* blin = (const float*)d_in[10];
  float* out = (float*)d_out;

  const size_t shmem = (size_t)H4 * H * sizeof(float);  // 41616 B (init overlay)
  hipFuncSetAttribute((const void*)lstm2_v10,
                      hipFuncAttributeMaxDynamicSharedMemorySize, (int)shmem);

  hipLaunchKernelGGL(lstm2_v10, dim3(GRID), dim3(BLK), shmem, stream,
                     x, Wih1, Whh1, bih1, bhh1, Wih2, Whh2, bih2, bhh2,
                     Wlin, blin, out);
}